// Round 1
// baseline (259.132 us; speedup 1.0000x reference)
//
#include <hip/hip_runtime.h>
#include <hip/hip_bf16.h>

#define B_    2
#define CIN   4
#define COUT  8
#define KK    4
#define DD    2
#define NN    224
#define FDIM  128
#define NH    218
#define NSUB  (NH*NH)      // 47524
#define NPERM 24

// all 24 permutations of {0,1,2,3} (order irrelevant: min over p)
__device__ static constexpr int PERM[NPERM][4] = {
  {0,1,2,3},{0,1,3,2},{0,2,1,3},{0,2,3,1},{0,3,1,2},{0,3,2,1},
  {1,0,2,3},{1,0,3,2},{1,2,0,3},{1,2,3,0},{1,3,0,2},{1,3,2,0},
  {2,0,1,3},{2,0,3,1},{2,1,0,3},{2,1,3,0},{2,3,0,1},{2,3,1,0},
  {3,0,1,2},{3,0,2,1},{3,1,0,2},{3,1,2,0},{3,2,0,1},{3,2,1,0}
};

// h_mean[b,f] = (2/nH) * sum_r w(r) * features[b,r,f]
__global__ void hmean_kernel(const float* __restrict__ features, float* __restrict__ out) {
  int t = blockIdx.x * blockDim.x + threadIdx.x;
  if (t >= B_ * FDIM) return;
  int b = t / FDIM, f = t - b * FDIM;
  const float* fb = features + (size_t)b * NN * FDIM + f;
  float acc = 0.f;
  for (int r = 0; r < NN; ++r) {
    int w = 0;
#pragma unroll
    for (int a = 0; a < KK; ++a) {
      int i0 = r - a * DD;
      if (0 <= i0 && i0 < NH) w++;
    }
    if (w) acc += (float)w * fb[(size_t)r * FDIM];
  }
  out[t] = acc * (2.0f / (float)NH);
}

__global__ __launch_bounds__(256) void sims_kernel(
    const float* __restrict__ graph, const float* __restrict__ types,
    const float* __restrict__ ksA, const float* __restrict__ krA,
    const float* __restrict__ kcA, float* __restrict__ simsOut)
{
  __shared__ float ls[COUT * CIN * 16];
  __shared__ float lr[COUT * CIN * 4];
  __shared__ float lc[COUT * CIN * 4];
  int t = threadIdx.x;
  for (int i = t; i < COUT * CIN * 16; i += 256) ls[i] = ksA[i];
  for (int i = t; i < COUT * CIN * 4; i += 256) { lr[i] = krA[i]; lc[i] = kcA[i]; }
  __syncthreads();

  int gid = blockIdx.x * 256 + t;
  if (gid >= B_ * NSUB) return;
  int b = gid / NSUB;
  int s = gid - b * NSUB;
  int ii = s / NH;
  int jj = s - ii * NH;

  const float* gb = graph + (size_t)b * CIN * NN * NN;
  const float* tb = types + (size_t)b * CIN * NN;

#pragma unroll 1
  for (int ci = 0; ci < CIN; ++ci) {
    float subv[16], rtv[4], ctv[4];
    const float* gi = gb + (size_t)ci * NN * NN;
    const float* ti = tb + ci * NN;
    float G2 = 0.f, T2r = 0.f, T2c = 0.f;
#pragma unroll
    for (int a = 0; a < KK; ++a) {
      const float* row = gi + (size_t)(ii + a * DD) * NN + jj;
#pragma unroll
      for (int bb = 0; bb < KK; ++bb) {
        float v = row[bb * DD];
        subv[a * 4 + bb] = v;
        G2 += v * v;
      }
      float rv = ti[ii + a * DD];
      float cv = ti[jj + a * DD];
      rtv[a] = rv; ctv[a] = cv;
      T2r += rv * rv; T2c += cv * cv;
    }
    float base0 = G2 + T2r + T2c;
#pragma unroll 1
    for (int o = 0; o < COUT; ++o) {
      float kS[16], kR[4], kC[4];
      const float* pS = ls + (o * CIN + ci) * 16;
      const float* pR = lr + (o * CIN + ci) * 4;
      const float* pC = lc + (o * CIN + ci) * 4;
      float K2 = 0.f;
#pragma unroll
      for (int u = 0; u < 16; ++u) { kS[u] = pS[u]; K2 += kS[u] * kS[u]; }
#pragma unroll
      for (int u = 0; u < 4; ++u) {
        kR[u] = pR[u]; kC[u] = pC[u];
        K2 += kR[u] * kR[u] + kC[u] * kC[u];
      }
      float base = base0 + K2;
      float best = 3.4e38f;
#pragma unroll
      for (int p = 0; p < NPERM; ++p) {
        float cr = 0.f;
#pragma unroll
        for (int a = 0; a < 4; ++a) {
#pragma unroll
          for (int bb = 0; bb < 4; ++bb)
            cr += subv[a * 4 + bb] * kS[PERM[p][a] * 4 + PERM[p][bb]];
          cr += rtv[a] * kR[PERM[p][a]] + ctv[a] * kC[PERM[p][a]];
        }
        float tot = base - 2.f * cr;
        best = fminf(best, tot);
      }
      simsOut[((size_t)(b * COUT * CIN) + o * CIN + ci) * NSUB + s] = best;
    }
  }
}

// one block per (b,c): max -> sumexp -> rewrite in place as (1-softmax)/n_sub
__global__ __launch_bounds__(256) void softmax_kernel(float* __restrict__ sims) {
  int bc = blockIdx.x;
  float* row = sims + (size_t)bc * NSUB;
  __shared__ float red[256];
  int t = threadIdx.x;
  float m = -3.4e38f;
  for (int i = t; i < NSUB; i += 256) m = fmaxf(m, row[i]);
  red[t] = m;
  __syncthreads();
  for (int off = 128; off > 0; off >>= 1) {
    if (t < off) red[t] = fmaxf(red[t], red[t + off]);
    __syncthreads();
  }
  float mx = red[0];
  __syncthreads();
  float sum = 0.f;
  for (int i = t; i < NSUB; i += 256) sum += expf(row[i] - mx);
  red[t] = sum;
  __syncthreads();
  for (int off = 128; off > 0; off >>= 1) {
    if (t < off) red[t] += red[t + off];
    __syncthreads();
  }
  float inv = 1.0f / red[0];
  const float scale = 1.0f / (float)NSUB;
  for (int i = t; i < NSUB; i += 256) {
    float e = expf(row[i] - mx) * inv;
    row[i] = (1.0f - e) * scale;
  }
}

extern "C" void kernel_launch(void* const* d_in, const int* in_sizes, int n_in,
                              void* d_out, int out_size, void* d_ws, size_t ws_size,
                              hipStream_t stream) {
  const float* graph    = (const float*)d_in[0];
  const float* types    = (const float*)d_in[1];
  const float* features = (const float*)d_in[2];
  const float* ks       = (const float*)d_in[3];
  const float* kr       = (const float*)d_in[4];
  const float* kc       = (const float*)d_in[5];
  float* out  = (float*)d_out;
  float* sims = out + B_ * FDIM;  // out_sim region, exactly B*32*NSUB floats

  hmean_kernel<<<1, 256, 0, stream>>>(features, out);
  int total = B_ * NSUB;
  sims_kernel<<<(total + 255) / 256, 256, 0, stream>>>(graph, types, ks, kr, kc, sims);
  softmax_kernel<<<B_ * COUT * CIN, 256, 0, stream>>>(sims);
}

// Round 2
// 120.771 us; speedup vs baseline: 2.1456x; 2.1456x over previous
//
#include <hip/hip_runtime.h>
#include <hip/hip_bf16.h>

#define B_    2
#define CIN   4
#define COUT  8
#define KK    4
#define DD    2
#define NN    224
#define FDIM  128
#define NH    218
#define NSUB  (NH*NH)      // 47524
#define NPERM 24
#define NROWS (B_*COUT*CIN)   // 64 softmax rows
#define CHUNK 1984            // 31 * 64
#define MB    ((NSUB + CHUNK - 1) / CHUNK)   // 24 chunk-blocks per row

__device__ static constexpr int PERM[NPERM][4] = {
  {0,1,2,3},{0,1,3,2},{0,2,1,3},{0,2,3,1},{0,3,1,2},{0,3,2,1},
  {1,0,2,3},{1,0,3,2},{1,2,0,3},{1,2,3,0},{1,3,0,2},{1,3,2,0},
  {2,0,1,3},{2,0,3,1},{2,1,0,3},{2,1,3,0},{2,3,0,1},{2,3,1,0},
  {3,0,1,2},{3,0,2,1},{3,1,0,2},{3,1,2,0},{3,2,0,1},{3,2,1,0}
};

// one wave per (b,f): lanes split r, shuffle-reduce
__global__ __launch_bounds__(64) void hmean_kernel(const float* __restrict__ features,
                                                   float* __restrict__ out) {
  int bf = blockIdx.x;              // 0..B_*FDIM-1
  int b = bf / FDIM, f = bf - b * FDIM;
  int lane = threadIdx.x;
  const float* fb = features + (size_t)b * NN * FDIM + f;
  float acc = 0.f;
  for (int r = lane; r < NN; r += 64) {
    int w = 0;
#pragma unroll
    for (int a = 0; a < KK; ++a) {
      int i0 = r - a * DD;
      if (0 <= i0 && i0 < NH) w++;
    }
    acc += (float)w * fb[(size_t)r * FDIM];
  }
#pragma unroll
  for (int off = 32; off > 0; off >>= 1) acc += __shfl_down(acc, off, 64);
  if (lane == 0) out[bf] = acc * (2.0f / (float)NH);
}

// thread per (b,ci,s); inner loop over o
__global__ __launch_bounds__(256) void sims_kernel(
    const float* __restrict__ graph, const float* __restrict__ types,
    const float* __restrict__ ksA, const float* __restrict__ krA,
    const float* __restrict__ kcA, float* __restrict__ simsOut)
{
  __shared__ float ls[COUT * CIN * 16];
  __shared__ float lr[COUT * CIN * 4];
  __shared__ float lc[COUT * CIN * 4];
  int t = threadIdx.x;
  for (int i = t; i < COUT * CIN * 16; i += 256) ls[i] = ksA[i];
  for (int i = t; i < COUT * CIN * 4; i += 256) { lr[i] = krA[i]; lc[i] = kcA[i]; }
  __syncthreads();

  int gid = blockIdx.x * 256 + t;
  if (gid >= B_ * CIN * NSUB) return;
  int bci = gid / NSUB;
  int s   = gid - bci * NSUB;
  int b   = bci / CIN;
  int ci  = bci - b * CIN;
  int ii  = s / NH;
  int jj  = s - ii * NH;

  const float* gi = graph + ((size_t)b * CIN + ci) * NN * NN;
  const float* ti = types + ((size_t)b * CIN + ci) * NN;

  float subv[16], rtv[4], ctv[4];
  float G2 = 0.f, T2r = 0.f, T2c = 0.f;
#pragma unroll
  for (int a = 0; a < KK; ++a) {
    const float* row = gi + (size_t)(ii + a * DD) * NN + jj;
#pragma unroll
    for (int bb = 0; bb < KK; ++bb) {
      float v = row[bb * DD];
      subv[a * 4 + bb] = v;
      G2 += v * v;
    }
    float rv = ti[ii + a * DD];
    float cv = ti[jj + a * DD];
    rtv[a] = rv; ctv[a] = cv;
    T2r += rv * rv; T2c += cv * cv;
  }
  float base0 = G2 + T2r + T2c;

#pragma unroll 1
  for (int o = 0; o < COUT; ++o) {
    float kS[16], kR[4], kC[4];
    const float4* pS4 = (const float4*)(ls + (o * CIN + ci) * 16);
    const float* pR = lr + (o * CIN + ci) * 4;
    const float* pC = lc + (o * CIN + ci) * 4;
    float K2 = 0.f;
#pragma unroll
    for (int u = 0; u < 4; ++u) {
      float4 v4 = pS4[u];
      kS[u*4+0] = v4.x; kS[u*4+1] = v4.y; kS[u*4+2] = v4.z; kS[u*4+3] = v4.w;
      K2 += v4.x*v4.x + v4.y*v4.y + v4.z*v4.z + v4.w*v4.w;
    }
#pragma unroll
    for (int u = 0; u < 4; ++u) {
      kR[u] = pR[u]; kC[u] = pC[u];
      K2 += kR[u] * kR[u] + kC[u] * kC[u];
    }
    float base = base0 + K2;
    float best = 3.4e38f;
#pragma unroll
    for (int p = 0; p < NPERM; ++p) {
      float cr = 0.f;
#pragma unroll
      for (int a = 0; a < 4; ++a) {
#pragma unroll
        for (int bb = 0; bb < 4; ++bb)
          cr += subv[a * 4 + bb] * kS[PERM[p][a] * 4 + PERM[p][bb]];
        cr += rtv[a] * kR[PERM[p][a]] + ctv[a] * kC[PERM[p][a]];
      }
      float tot = base - 2.f * cr;
      best = fminf(best, tot);
    }
    simsOut[(((size_t)b * COUT + o) * CIN + ci) * NSUB + s] = best;
  }
}

// pass A: per (row, chunk) partial max + sumexp
__global__ __launch_bounds__(256) void softmax_partial(const float* __restrict__ sims,
                                                       float* __restrict__ partial) {
  int blk = blockIdx.x;           // row * MB + chunk
  int row = blk / MB;
  int ch  = blk - row * MB;
  int base = ch * CHUNK;
  int n = NSUB - base; if (n > CHUNK) n = CHUNK;
  const float* rp = sims + (size_t)row * NSUB + base;
  int t = threadIdx.x;

  float v[8]; int cnt = 0;
  for (int i = t; i < n; i += 256) v[cnt++] = rp[i];

  __shared__ float red[256];
  float m = -3.4e38f;
  for (int u = 0; u < cnt; ++u) m = fmaxf(m, v[u]);
  red[t] = m; __syncthreads();
  for (int off = 128; off > 0; off >>= 1) {
    if (t < off) red[t] = fmaxf(red[t], red[t + off]);
    __syncthreads();
  }
  m = red[0]; __syncthreads();
  float l = 0.f;
  for (int u = 0; u < cnt; ++u) l += __expf(v[u] - m);
  red[t] = l; __syncthreads();
  for (int off = 128; off > 0; off >>= 1) {
    if (t < off) red[t] += red[t + off];
    __syncthreads();
  }
  if (t == 0) { partial[2 * blk] = m; partial[2 * blk + 1] = red[0]; }
}

// pass B: combine MB partials per row -> (M, 1/S)
__global__ __launch_bounds__(64) void softmax_combine(const float* __restrict__ partial,
                                                      float* __restrict__ stats) {
  int row = blockIdx.x;
  int t = threadIdx.x;
  float m = -3.4e38f, l = 0.f;
  if (t < MB) { m = partial[2 * (row * MB + t)]; l = partial[2 * (row * MB + t) + 1]; }
#pragma unroll
  for (int off = 32; off > 0; off >>= 1) m = fmaxf(m, __shfl_down(m, off, 64));
  m = __shfl(m, 0, 64);
  float contrib = (t < MB) ? l * __expf(partial[2 * (row * MB + t)] - m) : 0.f;
#pragma unroll
  for (int off = 32; off > 0; off >>= 1) contrib += __shfl_down(contrib, off, 64);
  if (t == 0) { stats[2 * row] = m; stats[2 * row + 1] = 1.0f / contrib; }
}

// pass C: rewrite in place
__global__ __launch_bounds__(256) void softmax_final(float* __restrict__ sims,
                                                     const float* __restrict__ stats) {
  int blk = blockIdx.x;
  int row = blk / MB;
  int ch  = blk - row * MB;
  int base = ch * CHUNK;
  int n = NSUB - base; if (n > CHUNK) n = CHUNK;
  float* rp = sims + (size_t)row * NSUB + base;
  float M = stats[2 * row], invS = stats[2 * row + 1];
  const float scale = 1.0f / (float)NSUB;
  for (int i = threadIdx.x; i < n; i += 256) {
    float e = __expf(rp[i] - M) * invS;
    rp[i] = (1.0f - e) * scale;
  }
}

extern "C" void kernel_launch(void* const* d_in, const int* in_sizes, int n_in,
                              void* d_out, int out_size, void* d_ws, size_t ws_size,
                              hipStream_t stream) {
  const float* graph    = (const float*)d_in[0];
  const float* types    = (const float*)d_in[1];
  const float* features = (const float*)d_in[2];
  const float* ks       = (const float*)d_in[3];
  const float* kr       = (const float*)d_in[4];
  const float* kc       = (const float*)d_in[5];
  float* out  = (float*)d_out;
  float* sims = out + B_ * FDIM;

  float* partial = (float*)d_ws;                    // NROWS*MB*2 floats
  float* stats   = partial + NROWS * MB * 2;        // NROWS*2 floats

  hmean_kernel<<<B_ * FDIM, 64, 0, stream>>>(features, out);
  int total = B_ * CIN * NSUB;
  sims_kernel<<<(total + 255) / 256, 256, 0, stream>>>(graph, types, ks, kr, kc, sims);
  softmax_partial<<<NROWS * MB, 256, 0, stream>>>(sims, partial);
  softmax_combine<<<NROWS, 64, 0, stream>>>(partial, stats);
  softmax_final<<<NROWS * MB, 256, 0, stream>>>(sims, stats);
}